// Round 6
// baseline (60.475 us; speedup 1.0000x reference)
//
#include <hip/hip_runtime.h>

#define D 64
#define CHARSET 128
#define GAMMA 1.0f
#define SPB 64          // segments per block
#define HROWS 32        // packed hist rows (2 segments per int)
#define HPAD 132        // padded row length in words (16B-aligned, bank-rotated)

typedef short s8v  __attribute__((ext_vector_type(8)));   // bf16x8 frag
typedef float f16v __attribute__((ext_vector_type(16)));  // fp32x16 accum

__device__ __forceinline__ short f32_to_bf16(float f) {
    unsigned u = __builtin_bit_cast(unsigned, f);
    unsigned r = (u + 0x7FFFu + ((u >> 16) & 1u)) >> 16;   // RNE
    return (short)r;
}

// preproc: start[g] = first char index whose segment >= 64*g; also init out.
// int4-vectorized: each thread owns chars [4q, 4q+4).
__global__ void preproc(const int* __restrict__ seg, int total, int nblocks,
                        int* __restrict__ start, float* __restrict__ out, float outv) {
    int q = blockIdx.x * blockDim.x + threadIdx.x;
    if (q == 0) out[0] = outv;
    int c0 = q * 4;
    if (c0 >= total) return;
    int v[4];
    if (c0 + 3 < total) { int4 w = *(const int4*)&seg[c0]; v[0]=w.x; v[1]=w.y; v[2]=w.z; v[3]=w.w; }
    else { for (int i = 0; i < 4; ++i) v[i] = (c0 + i < total) ? seg[c0 + i] : v[i>0?i-1:0]; }
    int prev = (c0 == 0) ? -1 : seg[c0 - 1];               // neighbor: L1-hit
    int lim = min(4, total - c0);
    for (int i = 0; i < lim; ++i) {
        int cur = v[i];
        for (int g = (prev >> 6) + 1; (g << 6) <= cur; ++g) start[g] = c0 + i;
        if (c0 + i == total - 1)
            for (int g = (cur >> 6) + 1; g <= nblocks; ++g) start[g] = total;
        prev = cur;
    }
}

__global__ void init_out(float* out, float v) {
    if (threadIdx.x == 0 && blockIdx.x == 0) out[0] = v;
}

// cooperative lower_bound (fallback path only)
__device__ __forceinline__ int lower_bound64(const int* __restrict__ seg,
                                             int lo, int hi, int target, int lane) {
    while (hi - lo > 64) {
        int step = (hi - lo) >> 6;
        int idx = lo + lane * step;
        int v = seg[idx];
        unsigned long long mask = __ballot(v < target);
        if (mask == 0ull) { hi = lo; break; }
        int k = 63 - __clzll(mask);
        int nhi = (k == 63) ? hi : (lo + (k + 1) * step);
        lo = lo + k * step; hi = nhi;
    }
    if (hi > lo) {
        int idx = lo + lane;
        int v = (idx < hi) ? seg[idx] : 0x7FFFFFFF;
        lo += __popcll(__ballot(v < target));
    }
    return lo;
}

template<bool USE_STARTS>
__global__ __launch_bounds__(256, 8) void attr_mfma_kernel(
    const int* __restrict__ char_ids,
    const int* __restrict__ seg_ids,
    const int* __restrict__ head_ids,
    const int* __restrict__ rel_ids,
    const float* __restrict__ char_emb,
    const float* __restrict__ rel_emb,
    const float* __restrict__ ent_emb,
    const int* __restrict__ start,
    float* __restrict__ out,
    int n_triples, int total_chars)
{
    __shared__ unsigned hist[HROWS][HPAD];   // 16.9 KB, 2 segments per word
    __shared__ int lds_hid[SPB];
    __shared__ int lds_rid[SPB];
    __shared__ float red[4];

    const int wib  = threadIdx.x >> 6;
    const int lane = threadIdx.x & 63;
    const int s0   = blockIdx.x * SPB;

    // zero histogram (vectorized: 4224 words = 1056 uint4)
    for (int i = threadIdx.x; i < HROWS * HPAD / 4; i += 256)
        ((uint4*)hist)[i] = make_uint4(0u, 0u, 0u, 0u);

    // stage this block's head/rel ids into LDS (independent of hist)
    {
        int t = threadIdx.x;
        if (t < SPB)
            lds_hid[t] = (s0 + t < n_triples) ? head_ids[s0 + t] : 0;
        else if (t < 2 * SPB)
            lds_rid[t - SPB] = (s0 + t - SPB < n_triples) ? rel_ids[s0 + t - SPB] : 0;
    }

    // ---- B fragments: emb -> registers, once per wave (32 VGPRs) ----
    const int cb = wib & 1, rb = wib >> 1;       // C tile (rows 32*rb, cols 32*cb)
    const int col = lane & 31, half = lane >> 5;
    s8v bfrag[8];
    #pragma unroll
    for (int st = 0; st < 8; ++st) {
        #pragma unroll
        for (int e = 0; e < 8; ++e) {
            int k = st * 16 + half * 8 + e;      // B: col=lane&31, k=(lane>>5)*8+e
            bfrag[st][e] = f32_to_bf16(char_emb[k * D + cb * 32 + col]);
        }
    }
    __syncthreads();   // hist zeroed, ids staged

    // ---- block's char range ----
    int c_begin, c_end;
    if (USE_STARTS) {
        c_begin = start[blockIdx.x];
        c_end   = start[blockIdx.x + 1];
    } else {
        c_begin = lower_bound64(seg_ids, 0, total_chars, s0, lane);
        c_end   = lower_bound64(seg_ids, c_begin, total_chars,
                                min(s0 + SPB, n_triples), lane);
    }

    // ---- histogram: one packed LDS atomic per char ----
    for (int c = c_begin + threadIdx.x; c < c_end; c += 256) {
        int sid = seg_ids[c];                    // coalesced
        int cid = char_ids[c];                   // coalesced
        unsigned off = (unsigned)(sid - s0);
        atomicAdd(&hist[off >> 1][cid], 1u << ((off & 1u) << 4));
    }
    __syncthreads();

    // ---- t tile via MFMA: C[64 seg][64 dim] = hist x emb ----
    f16v acc = (f16v)0.f;
    const int arow = rb * 32 + col;              // A: row=lane&31, k=(lane>>5)*8+e
    const int prow = arow >> 1;
    const unsigned sh = (arow & 1u) << 4;
    #pragma unroll
    for (int st = 0; st < 8; ++st) {
        int kbase = st * 16 + half * 8;
        uint4 c0 = *(const uint4*)&hist[prow][kbase];     // pair-broadcast reads
        uint4 c1 = *(const uint4*)&hist[prow][kbase + 4];
        s8v afrag;
        afrag[0] = f32_to_bf16((float)((c0.x >> sh) & 0xFFFFu));
        afrag[1] = f32_to_bf16((float)((c0.y >> sh) & 0xFFFFu));
        afrag[2] = f32_to_bf16((float)((c0.z >> sh) & 0xFFFFu));
        afrag[3] = f32_to_bf16((float)((c0.w >> sh) & 0xFFFFu));
        afrag[4] = f32_to_bf16((float)((c1.x >> sh) & 0xFFFFu));
        afrag[5] = f32_to_bf16((float)((c1.y >> sh) & 0xFFFFu));
        afrag[6] = f32_to_bf16((float)((c1.z >> sh) & 0xFFFFu));
        afrag[7] = f32_to_bf16((float)((c1.w >> sh) & 0xFFFFu));
        acc = __builtin_amdgcn_mfma_f32_32x32x16_bf16(afrag, bfrag[st], acc, 0, 0, 0);
    }

    // ---- epilogue: part += |h + r - t| over my 16 C elements ----
    // C layout: col=lane&31, row=(reg&3)+8*(reg>>2)+4*(lane>>5)
    float part = 0.f;
    const int dim = cb * 32 + col;
    #pragma unroll
    for (int reg = 0; reg < 16; ++reg) {
        int srow = (reg & 3) + 8 * (reg >> 2) + 4 * half;
        int s = s0 + rb * 32 + srow;
        if (s < n_triples) {
            int hid = lds_hid[rb * 32 + srow];                // LDS broadcast
            int rid = lds_rid[rb * 32 + srow];
            float h = ent_emb[(size_t)hid * D + dim];         // 128B/half gather
            float r = rel_emb[rid * D + dim];                 // tiny table, L1
            part += fabsf(h + r - acc[reg]);
            // max(dist+GAMMA,0)==dist+GAMMA; GAMMA added once as N*GAMMA
        }
    }

    // ---- reduce: wave -> block -> one atomic ----
    #pragma unroll
    for (int off = 32; off > 0; off >>= 1)
        part += __shfl_down(part, off, 64);
    if (lane == 0) red[wib] = part;
    __syncthreads();
    if (threadIdx.x == 0)
        atomicAdd(out, red[0] + red[1] + red[2] + red[3]);
}

extern "C" void kernel_launch(void* const* d_in, const int* in_sizes, int n_in,
                              void* d_out, int out_size, void* d_ws, size_t ws_size,
                              hipStream_t stream) {
    const int*   char_ids = (const int*)  d_in[0];
    const int*   seg_ids  = (const int*)  d_in[1];
    const int*   head_ids = (const int*)  d_in[2];
    const int*   rel_ids  = (const int*)  d_in[3];
    const float* char_emb = (const float*)d_in[4];
    const float* rel_emb  = (const float*)d_in[5];
    const float* ent_emb  = (const float*)d_in[6];
    float* out = (float*)d_out;

    const int total_chars = in_sizes[0];
    const int n_triples   = in_sizes[2];
    const int nblocks = (n_triples + SPB - 1) / SPB;
    const float outv = (float)n_triples * GAMMA;

    int* start = (int*)d_ws;
    if (ws_size >= (size_t)(nblocks + 1) * sizeof(int)) {
        const int pthreads = (total_chars + 3) / 4;
        preproc<<<(pthreads + 255) / 256, 256, 0, stream>>>(
            seg_ids, total_chars, nblocks, start, out, outv);
        attr_mfma_kernel<true><<<nblocks, 256, 0, stream>>>(
            char_ids, seg_ids, head_ids, rel_ids,
            char_emb, rel_emb, ent_emb, start, out, n_triples, total_chars);
    } else {
        init_out<<<1, 64, 0, stream>>>(out, outv);
        attr_mfma_kernel<false><<<nblocks, 256, 0, stream>>>(
            char_ids, seg_ids, head_ids, rel_ids,
            char_emb, rel_emb, ent_emb, start, out, n_triples, total_chars);
    }
}

// Round 7
// 50.293 us; speedup vs baseline: 1.2024x; 1.2024x over previous
//
#include <hip/hip_runtime.h>

#define D 64
#define CHARSET 128
#define GAMMA 1.0f
#define SPB 64          // segments per block
#define HROWS 32        // packed hist rows (2 segments per int)
#define HPAD 132        // padded row length in words (16B-aligned, bank-rotated)

typedef short s8v  __attribute__((ext_vector_type(8)));   // bf16x8 frag
typedef float f16v __attribute__((ext_vector_type(16)));  // fp32x16 accum

__device__ __forceinline__ short f32_to_bf16(float f) {
    unsigned u = __builtin_bit_cast(unsigned, f);
    unsigned r = (u + 0x7FFFu + ((u >> 16) & 1u)) >> 16;   // RNE
    return (short)r;
}

// preproc: start[g] = first char index whose segment >= 64*g.
// int4-vectorized: each thread owns chars [4q, 4q+4).
__global__ void preproc(const int* __restrict__ seg, int total, int nblocks,
                        int* __restrict__ start) {
    int q = blockIdx.x * blockDim.x + threadIdx.x;
    int c0 = q * 4;
    if (c0 >= total) return;
    int v[4];
    if (c0 + 3 < total) { int4 w = *(const int4*)&seg[c0]; v[0]=w.x; v[1]=w.y; v[2]=w.z; v[3]=w.w; }
    else { for (int i = 0; i < 4; ++i) v[i] = (c0 + i < total) ? seg[c0 + i] : v[i>0?i-1:0]; }
    int prev = (c0 == 0) ? -1 : seg[c0 - 1];               // neighbor: L1-hit
    int lim = min(4, total - c0);
    for (int i = 0; i < lim; ++i) {
        int cur = v[i];
        for (int g = (prev >> 6) + 1; (g << 6) <= cur; ++g) start[g] = c0 + i;
        if (c0 + i == total - 1)
            for (int g = (cur >> 6) + 1; g <= nblocks; ++g) start[g] = total;
        prev = cur;
    }
}

// final: out[0] = sum(partials) + base   (no same-address atomic anywhere)
__global__ void reduce_partials(const float* __restrict__ p, int n,
                                float* __restrict__ out, float base) {
    __shared__ float red[4];
    float acc = 0.f;
    for (int i = threadIdx.x; i < n; i += 256) acc += p[i];
    #pragma unroll
    for (int off = 32; off > 0; off >>= 1) acc += __shfl_down(acc, off, 64);
    int wib = threadIdx.x >> 6, lane = threadIdx.x & 63;
    if (lane == 0) red[wib] = acc;
    __syncthreads();
    if (threadIdx.x == 0) out[0] = red[0] + red[1] + red[2] + red[3] + base;
}

__global__ void init_out(float* out, float v) {
    if (threadIdx.x == 0 && blockIdx.x == 0) out[0] = v;
}

// cooperative lower_bound (fallback path only)
__device__ __forceinline__ int lower_bound64(const int* __restrict__ seg,
                                             int lo, int hi, int target, int lane) {
    while (hi - lo > 64) {
        int step = (hi - lo) >> 6;
        int idx = lo + lane * step;
        int v = seg[idx];
        unsigned long long mask = __ballot(v < target);
        if (mask == 0ull) { hi = lo; break; }
        int k = 63 - __clzll(mask);
        int nhi = (k == 63) ? hi : (lo + (k + 1) * step);
        lo = lo + k * step; hi = nhi;
    }
    if (hi > lo) {
        int idx = lo + lane;
        int v = (idx < hi) ? seg[idx] : 0x7FFFFFFF;
        lo += __popcll(__ballot(v < target));
    }
    return lo;
}

template<bool USE_STARTS>
__global__ __launch_bounds__(256, 8) void attr_mfma_kernel(
    const int* __restrict__ char_ids,
    const int* __restrict__ seg_ids,
    const int* __restrict__ head_ids,
    const int* __restrict__ rel_ids,
    const float* __restrict__ char_emb,
    const float* __restrict__ rel_emb,
    const float* __restrict__ ent_emb,
    const int* __restrict__ start,
    float* __restrict__ partials,      // USE_STARTS: per-block slot; else out
    int n_triples, int total_chars)
{
    __shared__ unsigned hist[HROWS][HPAD];   // 16.9 KB, 2 segments per word
    __shared__ int lds_hid[SPB];
    __shared__ int lds_rid[SPB];
    __shared__ float red[4];

    const int wib  = threadIdx.x >> 6;
    const int lane = threadIdx.x & 63;
    const int s0   = blockIdx.x * SPB;

    // zero histogram (vectorized)
    for (int i = threadIdx.x; i < HROWS * HPAD / 4; i += 256)
        ((uint4*)hist)[i] = make_uint4(0u, 0u, 0u, 0u);

    // stage this block's head/rel ids into LDS
    {
        int t = threadIdx.x;
        if (t < SPB)
            lds_hid[t] = (s0 + t < n_triples) ? head_ids[s0 + t] : 0;
        else if (t < 2 * SPB)
            lds_rid[t - SPB] = (s0 + t - SPB < n_triples) ? rel_ids[s0 + t - SPB] : 0;
    }

    // ---- B fragments: emb -> registers, once per wave (32 VGPRs) ----
    const int cb = wib & 1, rb = wib >> 1;       // C tile (rows 32*rb, cols 32*cb)
    const int col = lane & 31, half = lane >> 5;
    s8v bfrag[8];
    #pragma unroll
    for (int st = 0; st < 8; ++st) {
        #pragma unroll
        for (int e = 0; e < 8; ++e) {
            int k = st * 16 + half * 8 + e;      // B: col=lane&31, k=(lane>>5)*8+e
            bfrag[st][e] = f32_to_bf16(char_emb[k * D + cb * 32 + col]);
        }
    }
    __syncthreads();   // hist zeroed, ids staged

    // ---- block's char range ----
    int c_begin, c_end;
    if (USE_STARTS) {
        c_begin = start[blockIdx.x];
        c_end   = start[blockIdx.x + 1];
    } else {
        c_begin = lower_bound64(seg_ids, 0, total_chars, s0, lane);
        c_end   = lower_bound64(seg_ids, c_begin, total_chars,
                                min(s0 + SPB, n_triples), lane);
    }

    // ---- histogram: one packed LDS atomic per char ----
    for (int c = c_begin + threadIdx.x; c < c_end; c += 256) {
        int sid = seg_ids[c];                    // coalesced
        int cid = char_ids[c];                   // coalesced
        unsigned off = (unsigned)(sid - s0);
        atomicAdd(&hist[off >> 1][cid], 1u << ((off & 1u) << 4));
    }
    __syncthreads();

    // ---- t tile via MFMA: C[64 seg][64 dim] = hist x emb ----
    f16v acc = (f16v)0.f;
    const int arow = rb * 32 + col;              // A: row=lane&31, k=(lane>>5)*8+e
    const int prow = arow >> 1;
    const unsigned sh = (arow & 1u) << 4;
    #pragma unroll
    for (int st = 0; st < 8; ++st) {
        int kbase = st * 16 + half * 8;
        uint4 c0 = *(const uint4*)&hist[prow][kbase];
        uint4 c1 = *(const uint4*)&hist[prow][kbase + 4];
        s8v afrag;
        afrag[0] = f32_to_bf16((float)((c0.x >> sh) & 0xFFFFu));
        afrag[1] = f32_to_bf16((float)((c0.y >> sh) & 0xFFFFu));
        afrag[2] = f32_to_bf16((float)((c0.z >> sh) & 0xFFFFu));
        afrag[3] = f32_to_bf16((float)((c0.w >> sh) & 0xFFFFu));
        afrag[4] = f32_to_bf16((float)((c1.x >> sh) & 0xFFFFu));
        afrag[5] = f32_to_bf16((float)((c1.y >> sh) & 0xFFFFu));
        afrag[6] = f32_to_bf16((float)((c1.z >> sh) & 0xFFFFu));
        afrag[7] = f32_to_bf16((float)((c1.w >> sh) & 0xFFFFu));
        acc = __builtin_amdgcn_mfma_f32_32x32x16_bf16(afrag, bfrag[st], acc, 0, 0, 0);
    }

    // ---- epilogue: part += |h + r - t| over my 16 C elements ----
    float part = 0.f;
    const int dim = cb * 32 + col;
    #pragma unroll
    for (int reg = 0; reg < 16; ++reg) {
        int srow = (reg & 3) + 8 * (reg >> 2) + 4 * half;
        int s = s0 + rb * 32 + srow;
        if (s < n_triples) {
            int hid = lds_hid[rb * 32 + srow];                // LDS broadcast
            int rid = lds_rid[rb * 32 + srow];
            float h = ent_emb[(size_t)hid * D + dim];         // 128B/half gather
            float r = rel_emb[rid * D + dim];                 // tiny table, L1
            part += fabsf(h + r - acc[reg]);
        }
    }

    // ---- reduce: wave -> block -> per-block slot (no global contention) ----
    #pragma unroll
    for (int off = 32; off > 0; off >>= 1)
        part += __shfl_down(part, off, 64);
    if (lane == 0) red[wib] = part;
    __syncthreads();
    if (threadIdx.x == 0) {
        float v = red[0] + red[1] + red[2] + red[3];
        if (USE_STARTS) partials[blockIdx.x] = v;    // plain store, private line
        else            atomicAdd(partials, v);      // fallback only
    }
}

extern "C" void kernel_launch(void* const* d_in, const int* in_sizes, int n_in,
                              void* d_out, int out_size, void* d_ws, size_t ws_size,
                              hipStream_t stream) {
    const int*   char_ids = (const int*)  d_in[0];
    const int*   seg_ids  = (const int*)  d_in[1];
    const int*   head_ids = (const int*)  d_in[2];
    const int*   rel_ids  = (const int*)  d_in[3];
    const float* char_emb = (const float*)d_in[4];
    const float* rel_emb  = (const float*)d_in[5];
    const float* ent_emb  = (const float*)d_in[6];
    float* out = (float*)d_out;

    const int total_chars = in_sizes[0];
    const int n_triples   = in_sizes[2];
    const int nblocks = (n_triples + SPB - 1) / SPB;
    const float base = (float)n_triples * GAMMA;

    int*   start    = (int*)d_ws;                       // [0 .. nblocks]
    float* partials = (float*)d_ws + (nblocks + 1);     // [0 .. nblocks)
    const size_t need = (size_t)(2 * nblocks + 1) * sizeof(int);

    if (ws_size >= need) {
        const int pthreads = (total_chars + 3) / 4;
        preproc<<<(pthreads + 255) / 256, 256, 0, stream>>>(
            seg_ids, total_chars, nblocks, start);
        attr_mfma_kernel<true><<<nblocks, 256, 0, stream>>>(
            char_ids, seg_ids, head_ids, rel_ids,
            char_emb, rel_emb, ent_emb, start, partials, n_triples, total_chars);
        reduce_partials<<<1, 256, 0, stream>>>(partials, nblocks, out, base);
    } else {
        init_out<<<1, 64, 0, stream>>>(out, base);
        attr_mfma_kernel<false><<<nblocks, 256, 0, stream>>>(
            char_ids, seg_ids, head_ids, rel_ids,
            char_emb, rel_emb, ent_emb, start, out, n_triples, total_chars);
    }
}

// Round 8
// 47.373 us; speedup vs baseline: 1.2766x; 1.0616x over previous
//
#include <hip/hip_runtime.h>

#define D 64
#define CHARSET 128
#define GAMMA 1.0f
#define SPW 16          // segments per wave
#define HROWS 8         // packed hist rows per wave (2 segs/word)
#define HPADW 132       // padded row length in words

typedef short s8v __attribute__((ext_vector_type(8)));   // bf16x8
typedef float f4v __attribute__((ext_vector_type(4)));   // fp32x4 accum

__device__ __forceinline__ short f32_to_bf16(float f) {
    unsigned u = __builtin_bit_cast(unsigned, f);
    unsigned r = (u + 0x7FFFu + ((u >> 16) & 1u)) >> 16;   // RNE
    return (short)r;
}

// build bf16 transposed table tabT[dim][k] (64 x 128)
__global__ void preproc_table(const float* __restrict__ emb, unsigned short* __restrict__ tabT) {
    int idx = blockIdx.x * 256 + threadIdx.x;   // idx = d*128 + k
    if (idx < D * CHARSET) {
        int d = idx >> 7, k = idx & 127;
        tabT[idx] = (unsigned short)f32_to_bf16(emb[k * D + d]);
    }
}

// start[g] = first char index whose segment >= 16*g
__global__ void preproc(const int* __restrict__ seg, int total, int nwaves,
                        int* __restrict__ start) {
    int q = blockIdx.x * blockDim.x + threadIdx.x;
    int c0 = q * 4;
    if (c0 >= total) return;
    int v[4];
    if (c0 + 3 < total) { int4 w = *(const int4*)&seg[c0]; v[0]=w.x; v[1]=w.y; v[2]=w.z; v[3]=w.w; }
    else { for (int i = 0; i < 4; ++i) v[i] = (c0 + i < total) ? seg[c0 + i] : v[i>0?i-1:0]; }
    int prev = (c0 == 0) ? -1 : seg[c0 - 1];
    int lim = min(4, total - c0);
    for (int i = 0; i < lim; ++i) {
        int cur = v[i];
        for (int g = (prev >> 4) + 1; (g << 4) <= cur; ++g) start[g] = c0 + i;
        if (c0 + i == total - 1)
            for (int g = (cur >> 4) + 1; g <= nwaves; ++g) start[g] = total;
        prev = cur;
    }
}

__global__ void reduce_partials(const float* __restrict__ p, int n,
                                float* __restrict__ out, float base) {
    __shared__ float red[16];
    float acc = 0.f;
    int nt4 = n >> 2;
    const float4* p4 = (const float4*)p;
    for (int i = threadIdx.x; i < nt4; i += 1024) { float4 v = p4[i]; acc += v.x + v.y + v.z + v.w; }
    for (int i = (nt4 << 2) + threadIdx.x; i < n; i += 1024) acc += p[i];
    #pragma unroll
    for (int off = 32; off > 0; off >>= 1) acc += __shfl_down(acc, off, 64);
    int wid = threadIdx.x >> 6, lane = threadIdx.x & 63;
    if (lane == 0) red[wid] = acc;
    __syncthreads();
    if (threadIdx.x == 0) { float s = base; for (int i = 0; i < 16; ++i) s += red[i]; out[0] = s; }
}

__global__ void init_out(float* out, float v) {
    if (threadIdx.x == 0 && blockIdx.x == 0) out[0] = v;
}

// in-wave cooperative lower_bound (fallback only)
__device__ __forceinline__ int lower_bound64(const int* __restrict__ seg,
                                             int lo, int hi, int target, int lane) {
    while (hi - lo > 64) {
        int step = (hi - lo) >> 6;
        int idx = lo + lane * step;
        int v = seg[idx];
        unsigned long long mask = __ballot(v < target);
        if (mask == 0ull) { hi = lo; break; }
        int k = 63 - __clzll(mask);
        int nhi = (k == 63) ? hi : (lo + (k + 1) * step);
        lo = lo + k * step; hi = nhi;
    }
    if (hi > lo) {
        int idx = lo + lane;
        int v = (idx < hi) ? seg[idx] : 0x7FFFFFFF;
        lo += __popcll(__ballot(v < target));
    }
    return lo;
}

// Barrier-free: each wave owns SPW=16 segments end-to-end. No __syncthreads.
template<bool USE_WS>
__global__ __launch_bounds__(256) void attr_wave_kernel(
    const int* __restrict__ char_ids,
    const int* __restrict__ seg_ids,
    const int* __restrict__ head_ids,
    const int* __restrict__ rel_ids,
    const float* __restrict__ char_emb,
    const float* __restrict__ rel_emb,
    const float* __restrict__ ent_emb,
    const unsigned short* __restrict__ tabT,   // bf16 [dim][k], USE_WS only
    const int* __restrict__ start,             // USE_WS only
    float* __restrict__ partials,              // USE_WS: per-wave slot; else out
    int n_triples, int total_chars, int nwaves)
{
    __shared__ __align__(16) unsigned hist[4][HROWS * HPADW];  // 16.9 KB total

    const int wib   = threadIdx.x >> 6;
    const int lane  = threadIdx.x & 63;
    const int gwave = blockIdx.x * 4 + wib;
    if (gwave >= nwaves) return;

    const int s0 = gwave * SPW;
    const int s1 = min(s0 + SPW, n_triples);
    unsigned* hq = hist[wib];

    // zero own hist quarter (264 uint4, wave-private)
    for (int i = lane; i < HROWS * HPADW / 4; i += 64)
        ((uint4*)hq)[i] = make_uint4(0u, 0u, 0u, 0u);

    // head/rel ids for my 4 output rows (row = (lane>>4)*4 + j)
    const int col = lane & 15, g4 = lane >> 4;
    int hid[4], rid[4];
    #pragma unroll
    for (int j = 0; j < 4; ++j) {
        int s = s0 + g4 * 4 + j;
        hid[j] = (s < n_triples) ? head_ids[s] : 0;
        rid[j] = (s < n_triples) ? rel_ids[s] : 0;
    }

    // my char range
    int cb, ce;
    if (USE_WS) { cb = start[gwave]; ce = start[gwave + 1]; }
    else {
        cb = lower_bound64(seg_ids, 0, total_chars, s0, lane);
        ce = lower_bound64(seg_ids, cb, total_chars, s1, lane);
    }

    // ---- histogram: 2-deep pipelined, wave-private, no barrier ----
    for (int c = cb + lane; c < ce; c += 128) {
        int c2 = c + 64;
        int sa = seg_ids[c], da = char_ids[c];
        int sb = 0, db = 0;
        bool hb = c2 < ce;
        if (hb) { sb = seg_ids[c2]; db = char_ids[c2]; }
        unsigned oa = (unsigned)(sa - s0);
        atomicAdd(&hq[(oa >> 1) * HPADW + da], 1u << ((oa & 1u) << 4));
        if (hb) {
            unsigned ob = (unsigned)(sb - s0);
            atomicAdd(&hq[(ob >> 1) * HPADW + db], 1u << ((ob & 1u) << 4));
        }
    }
    // same-wave RAW on LDS: ds ordering within wave, no barrier needed

    // ---- C[16 seg][64 dim] = hist x emb via 16 x mfma_16x16x32_bf16 ----
    // A: row=lane&15, k=(lane>>4)*8+e.  B: col=lane&15, k=(lane>>4)*8+e.
    // C: col=lane&15, row=(lane>>4)*4+reg.
    f4v acc[4] = {(f4v)0.f, (f4v)0.f, (f4v)0.f, (f4v)0.f};
    const int prow = col >> 1;
    const unsigned sh = (col & 1u) << 4;
    #pragma unroll 1
    for (int st = 0; st < 4; ++st) {
        int kbase = st * 32 + g4 * 8;
        uint4 c0 = *(const uint4*)&hq[prow * HPADW + kbase];
        uint4 c1 = *(const uint4*)&hq[prow * HPADW + kbase + 4];
        s8v afrag;
        afrag[0] = f32_to_bf16((float)((c0.x >> sh) & 0xFFFFu));
        afrag[1] = f32_to_bf16((float)((c0.y >> sh) & 0xFFFFu));
        afrag[2] = f32_to_bf16((float)((c0.z >> sh) & 0xFFFFu));
        afrag[3] = f32_to_bf16((float)((c0.w >> sh) & 0xFFFFu));
        afrag[4] = f32_to_bf16((float)((c1.x >> sh) & 0xFFFFu));
        afrag[5] = f32_to_bf16((float)((c1.y >> sh) & 0xFFFFu));
        afrag[6] = f32_to_bf16((float)((c1.z >> sh) & 0xFFFFu));
        afrag[7] = f32_to_bf16((float)((c1.w >> sh) & 0xFFFFu));
        #pragma unroll
        for (int ct = 0; ct < 4; ++ct) {
            s8v bfrag;
            if (USE_WS) {
                bfrag = *(const s8v*)&tabT[(size_t)(ct * 16 + col) * CHARSET + kbase];
            } else {
                #pragma unroll
                for (int e = 0; e < 8; ++e)
                    bfrag[e] = f32_to_bf16(char_emb[(kbase + e) * D + ct * 16 + col]);
            }
            acc[ct] = __builtin_amdgcn_mfma_f32_16x16x32_bf16(afrag, bfrag, acc[ct], 0, 0, 0);
        }
    }

    // ---- epilogue: part += |h + r - t| ----
    float part = 0.f;
    #pragma unroll
    for (int reg = 0; reg < 4; ++reg) {
        int s = s0 + g4 * 4 + reg;
        if (s < n_triples) {
            const float* hp = &ent_emb[(size_t)hid[reg] * D];
            const float* rp = &rel_emb[rid[reg] * D];
            #pragma unroll
            for (int ct = 0; ct < 4; ++ct) {
                int dim = ct * 16 + col;
                part += fabsf(hp[dim] + rp[dim] - acc[ct][reg]);
            }
        }
    }

    // ---- wave reduce -> per-wave slot (no contention) ----
    #pragma unroll
    for (int off = 32; off > 0; off >>= 1)
        part += __shfl_down(part, off, 64);
    if (lane == 0) {
        if (USE_WS) partials[gwave] = part;
        else        atomicAdd(partials, part);
    }
}

extern "C" void kernel_launch(void* const* d_in, const int* in_sizes, int n_in,
                              void* d_out, int out_size, void* d_ws, size_t ws_size,
                              hipStream_t stream) {
    const int*   char_ids = (const int*)  d_in[0];
    const int*   seg_ids  = (const int*)  d_in[1];
    const int*   head_ids = (const int*)  d_in[2];
    const int*   rel_ids  = (const int*)  d_in[3];
    const float* char_emb = (const float*)d_in[4];
    const float* rel_emb  = (const float*)d_in[5];
    const float* ent_emb  = (const float*)d_in[6];
    float* out = (float*)d_out;

    const int total_chars = in_sizes[0];
    const int n_triples   = in_sizes[2];
    const int nwaves  = (n_triples + SPW - 1) / SPW;
    const int nblocks = (nwaves + 3) / 4;
    const float base = (float)n_triples * GAMMA;

    // ws layout: tabT bf16[8192] | start int[nwaves+1] | partials float[nwaves]
    unsigned short* tabT   = (unsigned short*)d_ws;
    int*   start    = (int*)((char*)d_ws + D * CHARSET * sizeof(unsigned short));
    float* partials = (float*)(start + nwaves + 1);
    const size_t need = D * CHARSET * 2 + (size_t)(2 * nwaves + 1) * 4;

    if (ws_size >= need) {
        preproc_table<<<(D * CHARSET + 255) / 256, 256, 0, stream>>>(char_emb, tabT);
        const int pthreads = (total_chars + 3) / 4;
        preproc<<<(pthreads + 255) / 256, 256, 0, stream>>>(
            seg_ids, total_chars, nwaves, start);
        attr_wave_kernel<true><<<nblocks, 256, 0, stream>>>(
            char_ids, seg_ids, head_ids, rel_ids,
            char_emb, rel_emb, ent_emb, tabT, start, partials,
            n_triples, total_chars, nwaves);
        reduce_partials<<<1, 1024, 0, stream>>>(partials, nwaves, out, base);
    } else {
        init_out<<<1, 64, 0, stream>>>(out, base);
        attr_wave_kernel<false><<<nblocks, 256, 0, stream>>>(
            char_ids, seg_ids, head_ids, rel_ids,
            char_emb, rel_emb, ent_emb, nullptr, nullptr, out,
            n_triples, total_chars, nwaves);
    }
}

// Round 9
// 42.657 us; speedup vs baseline: 1.4177x; 1.1106x over previous
//
#include <hip/hip_runtime.h>

#define D 64
#define CHARSET 128
#define GAMMA 1.0f
#define SPW 16          // segments per wave
#define HROWS 8         // packed hist rows per wave (2 segs/word)
#define HPADW 132       // padded row length in words

typedef short s8v __attribute__((ext_vector_type(8)));   // bf16x8
typedef float f4v __attribute__((ext_vector_type(4)));   // fp32x4 accum

__device__ __forceinline__ short f32_to_bf16(float f) {
    unsigned u = __builtin_bit_cast(unsigned, f);
    unsigned r = (u + 0x7FFFu + ((u >> 16) & 1u)) >> 16;   // RNE
    return (short)r;
}

// Fused preproc:
//  - segstart[s] = first char index whose segment >= s   (s in [0, n_seg_pad])
//  - tabT[d*128+k] = bf16(emb[k*D+d])  (transposed char table)
__global__ void preproc(const int* __restrict__ seg, const float* __restrict__ emb,
                        int total, int n_seg_pad,
                        int* __restrict__ segstart, unsigned short* __restrict__ tabT) {
    int q = blockIdx.x * blockDim.x + threadIdx.x;
    if (q < D * CHARSET) {
        int d = q >> 7, k = q & 127;
        tabT[q] = (unsigned short)f32_to_bf16(emb[k * D + d]);
    }
    int c0 = q * 4;
    if (c0 >= total) return;
    int v[4];
    if (c0 + 3 < total) { int4 w = *(const int4*)&seg[c0]; v[0]=w.x; v[1]=w.y; v[2]=w.z; v[3]=w.w; }
    else { for (int i = 0; i < 4; ++i) v[i] = (c0 + i < total) ? seg[c0 + i] : v[i>0?i-1:0]; }
    int prev = (c0 == 0) ? -1 : seg[c0 - 1];               // neighbor: L1/L2-hit
    int lim = min(4, total - c0);
    for (int i = 0; i < lim; ++i) {
        int cur = v[i];
        for (int s = prev + 1; s <= cur; ++s) segstart[s] = c0 + i;
        if (c0 + i == total - 1)
            for (int s = cur + 1; s <= n_seg_pad; ++s) segstart[s] = total;
        prev = cur;
    }
}

__global__ void reduce_partials(const float* __restrict__ p, int n,
                                float* __restrict__ out, float base) {
    __shared__ float red[16];
    float acc = 0.f;
    int nt4 = n >> 2;
    const float4* p4 = (const float4*)p;
    for (int i = threadIdx.x; i < nt4; i += 1024) { float4 v = p4[i]; acc += v.x + v.y + v.z + v.w; }
    for (int i = (nt4 << 2) + threadIdx.x; i < n; i += 1024) acc += p[i];
    #pragma unroll
    for (int off = 32; off > 0; off >>= 1) acc += __shfl_down(acc, off, 64);
    int wid = threadIdx.x >> 6, lane = threadIdx.x & 63;
    if (lane == 0) red[wid] = acc;
    __syncthreads();
    if (threadIdx.x == 0) { float s = base; for (int i = 0; i < 16; ++i) s += red[i]; out[0] = s; }
}

__global__ void init_out(float* out, float v) {
    if (threadIdx.x == 0 && blockIdx.x == 0) out[0] = v;
}

// in-wave cooperative lower_bound (fallback only)
__device__ __forceinline__ int lower_bound64(const int* __restrict__ seg,
                                             int lo, int hi, int target, int lane) {
    while (hi - lo > 64) {
        int step = (hi - lo) >> 6;
        int idx = lo + lane * step;
        int v = seg[idx];
        unsigned long long mask = __ballot(v < target);
        if (mask == 0ull) { hi = lo; break; }
        int k = 63 - __clzll(mask);
        int nhi = (k == 63) ? hi : (lo + (k + 1) * step);
        lo = lo + k * step; hi = nhi;
    }
    if (hi > lo) {
        int idx = lo + lane;
        int v = (idx < hi) ? seg[idx] : 0x7FFFFFFF;
        lo += __popcll(__ballot(v < target));
    }
    return lo;
}

// Barrier-free: each wave owns SPW=16 segments end-to-end.
template<bool USE_WS>
__global__ __launch_bounds__(256) void attr_wave_kernel(
    const int* __restrict__ char_ids,
    const int* __restrict__ seg_ids,            // fallback only
    const int* __restrict__ head_ids,
    const int* __restrict__ rel_ids,
    const float* __restrict__ char_emb,
    const float* __restrict__ rel_emb,
    const float* __restrict__ ent_emb,
    const unsigned short* __restrict__ tabT,    // bf16 [dim][k], USE_WS only
    const int* __restrict__ segstart,           // USE_WS only
    float* __restrict__ partials,               // USE_WS: per-wave slot; else out
    int n_triples, int total_chars, int nwaves)
{
    __shared__ __align__(16) unsigned hist[4][HROWS * HPADW];  // 16.9 KB

    const int wib   = threadIdx.x >> 6;
    const int lane  = threadIdx.x & 63;
    const int gwave = blockIdx.x * 4 + wib;
    if (gwave >= nwaves) return;

    const int s0 = __builtin_amdgcn_readfirstlane(gwave * SPW);
    unsigned* hq = hist[wib];

    // zero own hist quarter (wave-private)
    for (int i = lane; i < HROWS * HPADW / 4; i += 64)
        ((uint4*)hq)[i] = make_uint4(0u, 0u, 0u, 0u);

    // head/rel ids for my 4 output rows (row = (lane>>4)*4 + j)
    const int col = lane & 15, g4 = lane >> 4;
    int hid[4], rid[4];
    #pragma unroll
    for (int j = 0; j < 4; ++j) {
        int s = s0 + g4 * 4 + j;
        hid[j] = (s < n_triples) ? head_ids[s] : 0;
        rid[j] = (s < n_triples) ? rel_ids[s] : 0;
    }

    if (USE_WS) {
        // ---- 17 wave-uniform boundaries -> SGPRs ----
        int b[SPW + 1];
        #pragma unroll
        for (int j = 0; j <= SPW; ++j) b[j] = segstart[s0 + j];
        const int cbg = b[0], ce = b[SPW];

        // ---- hist: char_ids only; 4-deep batched, branchless classify ----
        for (int c0 = cbg; c0 < ce; c0 += 256) {
            int cc[4], id[4];
            #pragma unroll
            for (int u = 0; u < 4; ++u) {
                cc[u] = c0 + u * 64 + lane;
                id[u] = (cc[u] < ce) ? char_ids[cc[u]] : -1;   // coalesced, independent
            }
            #pragma unroll
            for (int u = 0; u < 4; ++u) {
                if (id[u] >= 0) {
                    int c = cc[u];
                    int sid = 0;
                    #pragma unroll
                    for (int j = 1; j <= SPW; ++j) sid += (c >= b[j]) ? 1 : 0;  // v_cmp vs SGPR
                    atomicAdd(&hq[(sid >> 1) * HPADW + id[u]], 1u << ((sid & 1) << 4));
                }
            }
        }
    } else {
        int cb = lower_bound64(seg_ids, 0, total_chars, s0, lane);
        int ce = lower_bound64(seg_ids, cb, total_chars,
                               min(s0 + SPW, n_triples), lane);
        for (int c = cb + lane; c < ce; c += 64) {
            int sa = seg_ids[c], da = char_ids[c];
            unsigned oa = (unsigned)(sa - s0);
            atomicAdd(&hq[(oa >> 1) * HPADW + da], 1u << ((oa & 1u) << 4));
        }
    }
    // same-wave RAW on LDS: in-wave ds ordering, no barrier needed

    // ---- C[16 seg][64 dim] = hist x emb via 16 x mfma_16x16x32_bf16 ----
    // A: row=lane&15, k=(lane>>4)*8+e.  B: col=lane&15, k=(lane>>4)*8+e.
    // C: col=lane&15, row=(lane>>4)*4+reg.
    f4v acc[4] = {(f4v)0.f, (f4v)0.f, (f4v)0.f, (f4v)0.f};
    const int prow = col >> 1;
    const unsigned sh = (col & 1u) << 4;
    #pragma unroll 1
    for (int st = 0; st < 4; ++st) {
        int kbase = st * 32 + g4 * 8;
        uint4 c0 = *(const uint4*)&hq[prow * HPADW + kbase];
        uint4 c1 = *(const uint4*)&hq[prow * HPADW + kbase + 4];
        s8v afrag;
        afrag[0] = f32_to_bf16((float)((c0.x >> sh) & 0xFFFFu));
        afrag[1] = f32_to_bf16((float)((c0.y >> sh) & 0xFFFFu));
        afrag[2] = f32_to_bf16((float)((c0.z >> sh) & 0xFFFFu));
        afrag[3] = f32_to_bf16((float)((c0.w >> sh) & 0xFFFFu));
        afrag[4] = f32_to_bf16((float)((c1.x >> sh) & 0xFFFFu));
        afrag[5] = f32_to_bf16((float)((c1.y >> sh) & 0xFFFFu));
        afrag[6] = f32_to_bf16((float)((c1.z >> sh) & 0xFFFFu));
        afrag[7] = f32_to_bf16((float)((c1.w >> sh) & 0xFFFFu));
        #pragma unroll
        for (int ct = 0; ct < 4; ++ct) {
            s8v bfrag;
            if (USE_WS) {
                bfrag = *(const s8v*)&tabT[(size_t)(ct * 16 + col) * CHARSET + kbase];
            } else {
                #pragma unroll
                for (int e = 0; e < 8; ++e)
                    bfrag[e] = f32_to_bf16(char_emb[(kbase + e) * D + ct * 16 + col]);
            }
            acc[ct] = __builtin_amdgcn_mfma_f32_16x16x32_bf16(afrag, bfrag, acc[ct], 0, 0, 0);
        }
    }

    // ---- epilogue: part += |h + r - t| ----
    float part = 0.f;
    #pragma unroll
    for (int reg = 0; reg < 4; ++reg) {
        int s = s0 + g4 * 4 + reg;
        if (s < n_triples) {
            const float* hp = &ent_emb[(size_t)hid[reg] * D];
            const float* rp = &rel_emb[rid[reg] * D];
            #pragma unroll
            for (int ct = 0; ct < 4; ++ct) {
                int dim = ct * 16 + col;
                part += fabsf(hp[dim] + rp[dim] - acc[ct][reg]);
            }
        }
    }

    // ---- wave reduce -> per-wave slot ----
    #pragma unroll
    for (int off = 32; off > 0; off >>= 1)
        part += __shfl_down(part, off, 64);
    if (lane == 0) {
        if (USE_WS) partials[gwave] = part;
        else        atomicAdd(partials, part);
    }
}

extern "C" void kernel_launch(void* const* d_in, const int* in_sizes, int n_in,
                              void* d_out, int out_size, void* d_ws, size_t ws_size,
                              hipStream_t stream) {
    const int*   char_ids = (const int*)  d_in[0];
    const int*   seg_ids  = (const int*)  d_in[1];
    const int*   head_ids = (const int*)  d_in[2];
    const int*   rel_ids  = (const int*)  d_in[3];
    const float* char_emb = (const float*)d_in[4];
    const float* rel_emb  = (const float*)d_in[5];
    const float* ent_emb  = (const float*)d_in[6];
    float* out = (float*)d_out;

    const int total_chars = in_sizes[0];
    const int n_triples   = in_sizes[2];
    const int nwaves   = (n_triples + SPW - 1) / SPW;
    const int nblocks  = (nwaves + 3) / 4;
    const int n_seg_pad = nwaves * SPW;            // segstart[0..n_seg_pad]
    const float base = (float)n_triples * GAMMA;

    // ws layout: tabT bf16[8192] | segstart int[n_seg_pad+1] | partials float[nwaves]
    unsigned short* tabT = (unsigned short*)d_ws;
    int*   segstart = (int*)((char*)d_ws + D * CHARSET * sizeof(unsigned short));
    float* partials = (float*)(segstart + n_seg_pad + 1);
    const size_t need = D * CHARSET * 2 + (size_t)(n_seg_pad + 1 + nwaves) * 4;

    if (ws_size >= need) {
        const int pthreads = (total_chars + 3) / 4;
        preproc<<<(pthreads + 255) / 256, 256, 0, stream>>>(
            seg_ids, char_emb, total_chars, n_seg_pad, segstart, tabT);
        attr_wave_kernel<true><<<nblocks, 256, 0, stream>>>(
            char_ids, seg_ids, head_ids, rel_ids,
            char_emb, rel_emb, ent_emb, tabT, segstart, partials,
            n_triples, total_chars, nwaves);
        reduce_partials<<<1, 1024, 0, stream>>>(partials, nwaves, out, base);
    } else {
        init_out<<<1, 64, 0, stream>>>(out, base);
        attr_wave_kernel<false><<<nblocks, 256, 0, stream>>>(
            char_ids, seg_ids, head_ids, rel_ids,
            char_emb, rel_emb, ent_emb, nullptr, nullptr, out,
            n_triples, total_chars, nwaves);
    }
}